// Round 4
// baseline (106.804 us; speedup 1.0000x reference)
//
#include <hip/hip_runtime.h>

// DA-RNN (LSTM_price): T=10, D=45, H=45. fp32, single WG (256 thr), 1 launch.
// R4: attack the __syncthreads vmcnt(0) drain (hipcc drains ALL outstanding
// VMEM at every barrier -> R0's "prefetch at t0" gathers fully serialized
// before B0, ~20K scattered L1 line-lookups + cold HBM on the critical path;
// VALUBusy said 95% of the 45.6us kernel was stall).
//  - raw s_barrier (+sched_barrier fences) with explicit lgkmcnt(0) producer
//    flushes only -> gathers stay in flight across barriers, drain at USE.
//  - Whh_e staged coalesced (float4, waves2-3) into sR1; wave0 reads rows
//    from LDS during the Gx window (hidden). Wih_d gather moved post-B2.
//  - no sX/B0: wave1 gathers its score column + coalesced X into regs,
//    attn broadcast via in-wave shfl.
//  - tail fused: softmax in-wave (wave0), final fc via shfl (no sh1v).
//  - sR1 reused serially: Whh_e -> {Wfc[0:4050], W1c[4050:6075]}.
// Algebra (verified): Wa[0:90]/ba/b2/Whh_d dead; input attention
// time-invariant; decoder c2 = sig(i)*tanh(g).

static constexpr int NT = 10;
static constexpr int ND = 45;
static constexpr int NH = 45;
static constexpr int NG = 4 * NH; // 180
static constexpr int SWS = 48;    // padded sWi row stride (16B-aligned rows)

__device__ __forceinline__ float rcp_(float x) { return __builtin_amdgcn_rcpf(x); }
__device__ __forceinline__ float sigf(float x) { return rcp_(1.0f + __expf(-x)); }
__device__ __forceinline__ float tanh_(float x) { return 1.0f - 2.0f * rcp_(1.0f + __expf(2.0f * x)); }

__device__ __forceinline__ void lds_flush() {
    asm volatile("s_waitcnt lgkmcnt(0)" ::: "memory");
}
__device__ __forceinline__ void barrier_raw() {
    __builtin_amdgcn_sched_barrier(0);
    __builtin_amdgcn_s_barrier();
    __builtin_amdgcn_sched_barrier(0);
}

__global__ __launch_bounds__(256) void darnn_kernel(
    const float* __restrict__ X,      // [T,D]
    const float* __restrict__ Wa,     // [1,2H+T] (only [90:100] live)
    const float* __restrict__ Wih_e,  // [4H,D]
    const float* __restrict__ Whh_e,  // [4H,H]
    const float* __restrict__ bih_e,  // [4H]
    const float* __restrict__ bhh_e,  // [4H]
    const float* __restrict__ W1,     // [D,2H+D] (cols 90:135 live)
    const float* __restrict__ b1,     // [D]
    const float* __restrict__ W2,     // [1,D]
    const float* __restrict__ Wih_d,  // [4H,D]
    const float* __restrict__ bih_d,  // [4H]
    const float* __restrict__ bhh_d,  // [4H]
    const float* __restrict__ Wfc,    // [45,2H]
    const float* __restrict__ bfc,    // [45]
    float* __restrict__ out)          // [45]
{
    const int tid  = threadIdx.x;
    const int wave = tid >> 6;
    const int lane = tid & 63;
    const int g    = tid - 64;        // gate id for waves 1-3

    // 11,650 floats = 46.6 KB static LDS
    __shared__ __align__(16) float sR1[8100];   // Whh_e -> {Wfc, W1c}
    __shared__ __align__(16) float sWi[NT * SWS];
    __shared__ float sGx[NT * NG];
    __shared__ float shs[NT * NH];
    __shared__ float sdec[NT * NH];
    __shared__ float sat[NT];
    __shared__ float sctx[NH];
    __shared__ float sg[NG];
    __shared__ float sb1[ND];
    __shared__ float sW2v[ND];
    __shared__ float sbfcv[45];

    float we[45];
    float be = 0.0f;

    // ================= t0 -> B1 =================
    if (wave == 1) {
        // score column gather (needed first)
        float xc[NT];
        if (lane < ND) {
#pragma unroll
            for (int t = 0; t < NT; ++t) xc[t] = X[t * ND + lane];
        }
        // coalesced X for sWi (needed second)
        float xi[8];
#pragma unroll
        for (int r = 0; r < 8; ++r) {
            const int i = lane + r * 64;
            xi[r] = (i < NT * ND) ? X[i] : 0.0f;
        }
        // Wih_e row gather — first use at Gx (stays in flight across B1)
        {
            const float* wrE = Wih_e + g * ND;   // g = lane < 180 always here
#pragma unroll
            for (int d = 0; d < ND; ++d) we[d] = wrE[d];
            be = bih_e[g] + bhh_e[g];
        }
        // input attention (time-invariant)
        float acc = -1e30f;
        if (lane < ND) {
            acc = 0.0f;
#pragma unroll
            for (int t = 0; t < NT; ++t) acc += Wa[90 + t] * xc[t];
        }
        float m = acc;
        for (int off = 32; off; off >>= 1) m = fmaxf(m, __shfl_xor(m, off, 64));
        float e = (lane < ND) ? __expf(acc - m) : 0.0f;
        float s = e;
        for (int off = 32; off; off >>= 1) s += __shfl_xor(s, off, 64);
        const float p = e * rcp_(s);
        // sWi = attn(d) * X  (shfl executed by ALL lanes; only write guarded)
#pragma unroll
        for (int r = 0; r < 8; ++r) {
            const int i  = lane + r * 64;
            const int iw = (i < NT * ND) ? i : (NT * ND - 1);
            const int t  = iw / ND, d = iw - t * ND;
            const float av = __shfl(p, d, 64);
            if (i < NT * ND) sWi[t * SWS + d] = av * xi[r];
        }
        lds_flush();                      // sWi visible before barrier
    } else if (wave >= 2) {
        // Whh_e coalesced -> regs -> sR1 (507 lines instead of 8.1K lookups)
        const int b = tid - 128;          // 0..127
        float4 wc[16];
        const float4* s4 = (const float4*)Whh_e;
#pragma unroll
        for (int r = 0; r < 16; ++r) {
            const int i = b + r * 128;
            if (i < 2025) wc[r] = s4[i];
        }
        // Wih_e gather issued after (in-order vmcnt: ds_writes drain Whh only)
        if (g < NG) {
            const float* wrE = Wih_e + g * ND;
#pragma unroll
            for (int d = 0; d < ND; ++d) we[d] = wrE[d];
            be = bih_e[g] + bhh_e[g];
        }
        float4* d4 = (float4*)sR1;
#pragma unroll
        for (int r = 0; r < 16; ++r) {
            const int i = b + r * 128;
            if (i < 2025) d4[i] = wc[r];
        }
        lds_flush();                      // sR1(Whh) visible before barrier
    }
    barrier_raw(); // B1: sWi + sR1(Whh_e) ready; Wih_e gathers in flight

    // ================= B1 -> B2 =================
    float w0[45], w1[45], w2[45], w3[45];
    if (wave == 0) {
        // pull Whh rows from LDS (0.4us, hidden under Gx)
        const int j = (lane < 45) ? lane : 0;
#pragma unroll
        for (int k = 0; k < 45; ++k) {
            w0[k] = sR1[j * 45 + k];
            w1[k] = sR1[(45 + j) * 45 + k];
            w2[k] = sR1[(90 + j) * 45 + k];
            w3[k] = sR1[(135 + j) * 45 + k];
        }
    } else if (g < NG) {
        // Gx[t][g]: input-half encoder gates (we drains here, under compute)
        float acc[NT];
#pragma unroll
        for (int t = 0; t < NT; ++t) acc[t] = be;
#pragma unroll
        for (int d4 = 0; d4 < 11; ++d4) {
            const float wa = we[d4 * 4 + 0], wb = we[d4 * 4 + 1];
            const float wc_ = we[d4 * 4 + 2], wd_ = we[d4 * 4 + 3];
#pragma unroll
            for (int t = 0; t < NT; ++t) {
                const float4 v = *(const float4*)&sWi[t * SWS + d4 * 4];
                acc[t] += wa * v.x + wb * v.y + wc_ * v.z + wd_ * v.w;
            }
        }
#pragma unroll
        for (int t = 0; t < NT; ++t) acc[t] += we[44] * sWi[t * SWS + 44];
#pragma unroll
        for (int t = 0; t < NT; ++t) sGx[t * NG + g] = acc[t];
    }
    lds_flush();   // wave0: reads done before sR1 overwrite; others: sGx visible
    barrier_raw(); // B2: sGx ready, sR1 free

    // ================= B2 -> B3 (fork) =================
    float wd[45];
    float bd = 0.0f;
    if (wave == 0) {
        // serial 10-step recurrence: pure VALU + readlane, no barriers
        const int j = (lane < 45) ? lane : 0;
        float h = 0.0f, c = 0.0f;
        for (int t = 0; t < NT; ++t) {
            float a0 = sGx[t * NG + j];
            float a1 = sGx[t * NG + 45 + j];
            float a2 = sGx[t * NG + 90 + j];
            float a3 = sGx[t * NG + 135 + j];
#pragma unroll
            for (int k = 0; k < 45; ++k) {
                const float hk = __shfl(h, k, 64);
                a0 += w0[k] * hk; a1 += w1[k] * hk;
                a2 += w2[k] * hk; a3 += w3[k] * hk;
            }
            c = sigf(a1) * c + sigf(a0) * tanh_(a2);
            h = sigf(a3) * tanh_(c);
            if (lane < 45) shs[t * NH + lane] = h;
        }
    } else {
        const int i0 = tid - 64; // 0..191
        { // Wfc -> sR1[0:4050], coalesced float2
            const float2* s2 = (const float2*)Wfc;
            float2* d2 = (float2*)sR1;
            for (int i = i0; i < 2025; i += 192) d2[i] = s2[i];
        }
        // W1 live cols -> sR1[4050:6075]
        for (int i = i0; i < ND * ND; i += 192) {
            const int r = i / 45, cc = i - r * 45;
            sR1[4050 + i] = W1[r * 135 + 90 + cc];
        }
        if (i0 < 45) { sb1[i0] = b1[i0]; sW2v[i0] = W2[i0]; sbfcv[i0] = bfc[i0]; }
        // Wih_d gather LAST: stays in flight until the sg phase (~10us away)
        if (g < NG) {
            const float* wrD = Wih_d + g * ND;
#pragma unroll
            for (int d = 0; d < ND; ++d) wd[d] = wrD[d];
            bd = bih_d[g] + bhh_d[g];
        }
    }
    lds_flush();
    barrier_raw(); // B3: shs + sR1{Wfc,W1c} + small arrays ready

    // ================= decoder temporal attention =================
    for (int i = tid; i < NT * NH; i += 256) {
        const int t = i / NH, k = i - t * NH;
        const float* wr = sR1 + 4050 + k * ND;
        const float* hv = shs + t * NH;
        float a = sb1[k];
        for (int jj = 0; jj < ND; ++jj) a += wr[jj] * hv[jj];
        sdec[i] = sW2v[k] * tanh_(a);
    }
    lds_flush();
    barrier_raw(); // B4

    // scores + softmax fused in-wave on wave 0
    if (wave == 0) {
        float a = -1e30f;
        if (lane < NT) {
            a = 0.0f;
            for (int k = 0; k < NH; ++k) a += sdec[lane * NH + k];
        }
        float m = a;
        for (int off = 8; off; off >>= 1) m = fmaxf(m, __shfl_xor(m, off, 16));
        float e = (lane < NT) ? __expf(a - m) : 0.0f;
        float s = e;
        for (int off = 8; off; off >>= 1) s += __shfl_xor(s, off, 16);
        if (lane < NT) sat[lane] = e * rcp_(s); // b2 cancels in softmax
    }
    lds_flush();
    barrier_raw(); // B5

    // context
    if (tid < NH) {
        float a = 0.0f;
        for (int t = 0; t < NT; ++t) a += sat[t] * shs[t * NH + tid];
        sctx[tid] = a;
    }
    lds_flush();
    barrier_raw(); // B6

    // decoder LSTM gates (h=c=0): wd drains HERE, long since arrived
    if (wave > 0 && g < NG) {
        float a = bd;
#pragma unroll
        for (int d = 0; d < 45; ++d) a += wd[d] * sctx[d];
        sg[g] = a;
    }
    lds_flush();
    barrier_raw(); // B7

    // h1 + final fc fused on wave 0 (shfl broadcast; no sh1v, no extra barrier)
    if (wave == 0) {
        float h1 = 0.0f, cxv = 0.0f;
        if (lane < 45) {
            const float ig = sigf(sg[lane]);
            const float gg = tanh_(sg[2 * NH + lane]);
            const float og = sigf(sg[3 * NH + lane]);
            h1  = og * tanh_(ig * gg); // c0 = 0
            cxv = sctx[lane];
        }
        const float* wr = sR1 + ((lane < 45) ? lane : 0) * (2 * NH);
        float a = (lane < 45) ? sbfcv[lane] : 0.0f;
        for (int jj = 0; jj < NH; ++jj) {
            const float h1j = __shfl(h1, jj, 64);
            const float cxj = __shfl(cxv, jj, 64);
            a += wr[jj] * h1j + wr[NH + jj] * cxj;
        }
        if (lane < 45) out[lane] = a;
    }
}

extern "C" void kernel_launch(void* const* d_in, const int* in_sizes, int n_in,
                              void* d_out, int out_size, void* d_ws, size_t ws_size,
                              hipStream_t stream) {
    const float* X     = (const float*)d_in[0];
    const float* Wa    = (const float*)d_in[1];
    // d_in[2] = ba — dead
    const float* Wih_e = (const float*)d_in[3];
    const float* Whh_e = (const float*)d_in[4];
    const float* bih_e = (const float*)d_in[5];
    const float* bhh_e = (const float*)d_in[6];
    const float* W1    = (const float*)d_in[7];
    const float* b1    = (const float*)d_in[8];
    const float* W2    = (const float*)d_in[9];
    // d_in[10] = b2 — dead
    const float* Wih_d = (const float*)d_in[11];
    // d_in[12] = Whh_d — dead
    const float* bih_d = (const float*)d_in[13];
    const float* bhh_d = (const float*)d_in[14];
    const float* Wfc   = (const float*)d_in[15];
    const float* bfc   = (const float*)d_in[16];
    float* out = (float*)d_out;

    darnn_kernel<<<dim3(1), dim3(256), 0, stream>>>(
        X, Wa, Wih_e, Whh_e, bih_e, bhh_e, W1, b1, W2,
        Wih_d, bih_d, bhh_d, Wfc, bfc, out);
}

// Round 5
// 105.958 us; speedup vs baseline: 1.0080x; 1.0080x over previous
//
#include <hip/hip_runtime.h>

// DA-RNN (LSTM_price): T=10, D=45, H=45. fp32 in/out/compute.
// Single workgroup (256 thr), single launch, latency-optimized:
//  - ALL cold global loads issued at t=0: wave 0 prefetches Whh_e into
//    180 VGPRs; each of 180 staging threads (waves 1-3) prefetches its
//    Wih_e row AND Wih_d row (+fused biases) into registers; waves 2-3
//    stage X into LDS concurrently. Fetch latency overlaps the
//    attention preamble instead of serializing after barriers.
//  - 10-step recurrence on wave 0: pure VALU + v_readlane (__shfl),
//    no LDS traffic, no barriers inside the loop.
//  - waves 1-3 stage Wfc / W1-live-cols during the chain (hidden).
// R5 note: final revert to the best-measured structure (103.0 us R3,
// 105.6 us R0, 103.4 us prior session — identical source; noise >=
// +/-2.6 us). Both redesigns failed to beat it:
//  - R1 (coalesced LDS round-trip for Whh/Wih): 108.9 (+ barriers on
//    the critical path; scattered t0 gathers were already hidden).
//  - R4 (raw s_barrier, lgkm-only fences, no vmcnt drains): 106.8 —
//    correct (absmax 0.0) but no gain: timed-loop inputs are L2-warm
//    (poison touches only the workspace), so the vmcnt(0) drain at B0
//    is cheap in the timed loop; R3's 45.6us profile was replay/cold
//    inflation, not the warm kernel.
// Metric decomposition: ~79 us = 2 mandatory 256MiB poison fills at
// ~85% HBM write peak (harness-side roofline) + ~20-25 us warm
// latency-bound kernel + launch gaps.
// Algebra (verified, rounds 3/5 passed): Wa[0:90]/ba/b2/Whh_d dead;
// input attention time-invariant; decoder c2 = sig(i)*tanh(g).

static constexpr int NT = 10;
static constexpr int ND = 45;
static constexpr int NH = 45;
static constexpr int NG = 4 * NH; // 180

__device__ __forceinline__ float rcp_(float x) { return __builtin_amdgcn_rcpf(x); }
__device__ __forceinline__ float sigf(float x) { return rcp_(1.0f + __expf(-x)); }
__device__ __forceinline__ float tanh_(float x) { return 1.0f - 2.0f * rcp_(1.0f + __expf(2.0f * x)); }

__global__ __launch_bounds__(256) void darnn_kernel(
    const float* __restrict__ X,      // [T,D]
    const float* __restrict__ Wa,     // [1,2H+T] (only [90:100] live)
    const float* __restrict__ Wih_e,  // [4H,D]
    const float* __restrict__ Whh_e,  // [4H,H]
    const float* __restrict__ bih_e,  // [4H]
    const float* __restrict__ bhh_e,  // [4H]
    const float* __restrict__ W1,     // [D,2H+D] (cols 90:135 live)
    const float* __restrict__ b1,     // [D]
    const float* __restrict__ W2,     // [1,D]
    const float* __restrict__ Wih_d,  // [4H,D]
    const float* __restrict__ bih_d,  // [4H]
    const float* __restrict__ bhh_d,  // [4H]
    const float* __restrict__ Wfc,    // [45,2H]
    const float* __restrict__ bfc,    // [45]
    float* __restrict__ out)          // [45]
{
    const int tid  = threadIdx.x;
    const int wave = tid >> 6;
    const int lane = tid & 63;
    const int g    = tid - 64;        // staging-thread gate id (waves 1-3)

    // static LDS total: 10,135 floats = 40,540 B (< 64 KB static limit)
    __shared__ float sX[NT * ND];
    __shared__ float sattn[ND];
    __shared__ float sWi[NT * ND];
    __shared__ float sGx[NT * NG];
    __shared__ float shs[NT * NH];
    __shared__ float sW1c[ND * ND];
    __shared__ float sWfc[45 * 2 * NH];
    __shared__ float sb1[ND];
    __shared__ float sW2v[ND];
    __shared__ float sbfcv[45];
    __shared__ float sat[NT];
    __shared__ float sctx[NH];
    __shared__ float sh1v[NH];
    __shared__ float sg[NG];
    __shared__ float sdec[NT * NH];

    // ---- t=0: issue ALL cold fetches ----
    float w0[45], w1[45], w2[45], w3[45]; // wave 0: Whh_e
    float we[45], wd[45];                 // waves 1-3 (g<180): Wih_e / Wih_d rows
    float be = 0.0f, bd = 0.0f;
    if (wave == 0) {
        const int j = (lane < 45) ? lane : 0; // lanes 45-63 duplicate row 0
        const float* r0 = Whh_e + (j)       * NH;
        const float* r1 = Whh_e + (45 + j)  * NH;
        const float* r2 = Whh_e + (90 + j)  * NH;
        const float* r3 = Whh_e + (135 + j) * NH;
#pragma unroll
        for (int k = 0; k < 45; ++k) {
            w0[k] = r0[k]; w1[k] = r1[k]; w2[k] = r2[k]; w3[k] = r3[k];
        }
    } else {
        if (g < NG) {
            const float* wrE = Wih_e + g * ND;
            const float* wrD = Wih_d + g * ND;
#pragma unroll
            for (int d = 0; d < 45; ++d) { we[d] = wrE[d]; wd[d] = wrD[d]; }
            be = bih_e[g] + bhh_e[g];
            bd = bih_d[g] + bhh_d[g];
        }
        if (wave >= 2)
            for (int i = tid - 128; i < NT * ND; i += 128) sX[i] = X[i];
    }
    __syncthreads(); // B0: sX ready

    // ---- input attention (time-invariant) + sWi, wave 1 only ----
    if (wave == 1) {
        float acc = -1e30f;
        if (lane < ND) {
            acc = 0.0f;
            for (int t = 0; t < NT; ++t) acc += Wa[90 + t] * sX[t * ND + lane];
        }
        float m = acc;
        for (int off = 32; off; off >>= 1) m = fmaxf(m, __shfl_xor(m, off, 64));
        float e = (lane < ND) ? __expf(acc - m) : 0.0f;
        float s = e;
        for (int off = 32; off; off >>= 1) s += __shfl_xor(s, off, 64);
        if (lane < ND) sattn[lane] = e * rcp_(s);
        __builtin_amdgcn_s_waitcnt(0);      // sattn visible within the wave
        __builtin_amdgcn_wave_barrier();
        for (int i = lane; i < NT * ND; i += 64) sWi[i] = sattn[i % ND] * sX[i];
    }
    __syncthreads(); // B1: sWi ready

    // ---- Gx[t][g]: input-half of encoder gates (weights already in regs) ----
    if (wave > 0 && g < NG) {
        float acc[NT];
#pragma unroll
        for (int t = 0; t < NT; ++t) acc[t] = be;
        for (int d = 0; d < ND; ++d) {
            const float wv = we[d];
#pragma unroll
            for (int t = 0; t < NT; ++t) acc[t] += wv * sWi[t * ND + d];
        }
#pragma unroll
        for (int t = 0; t < NT; ++t) sGx[t * NG + g] = acc[t];
    }
    __syncthreads(); // B2: sGx ready

    // ---- FORK: wave 0 serial recurrence; waves 1-3 stage decoder LDS ----
    if (wave == 0) {
        const int j = (lane < 45) ? lane : 0;
        float h = 0.0f, c = 0.0f;
        for (int t = 0; t < NT; ++t) {
            float a0 = sGx[t * NG + j];
            float a1 = sGx[t * NG + 45 + j];
            float a2 = sGx[t * NG + 90 + j];
            float a3 = sGx[t * NG + 135 + j];
#pragma unroll
            for (int k = 0; k < 45; ++k) {
                const float hk = __shfl(h, k, 64);
                a0 += w0[k] * hk; a1 += w1[k] * hk;
                a2 += w2[k] * hk; a3 += w3[k] * hk;
            }
            c = sigf(a1) * c + sigf(a0) * tanh_(a2);
            h = sigf(a3) * tanh_(c);
            if (lane < 45) shs[t * NH + lane] = h;
        }
    } else {
        const int i0 = tid - 64; // 0..191
        { // Wfc: 4050 floats = 2025 float2, coalesced
            const float2* s2 = (const float2*)Wfc;
            float2* d2 = (float2*)sWfc;
            for (int i = i0; i < 2025; i += 192) d2[i] = s2[i];
        }
        // W1 live columns (90:135 of each 135-wide row)
        for (int i = i0; i < ND * ND; i += 192) {
            const int r = i / 45, cc = i - r * 45;
            sW1c[i] = W1[r * 135 + 90 + cc];
        }
        if (i0 < 45) { sb1[i0] = b1[i0]; sW2v[i0] = W2[i0]; sbfcv[i0] = bfc[i0]; }
    }
    __syncthreads(); // B3

    // ---- decoder temporal attention ----
    for (int i = tid; i < NT * NH; i += 256) {
        const int t = i / NH, k = i - t * NH;
        const float* wr = sW1c + k * ND;
        const float* hv = shs + t * NH;
        float a = sb1[k];
        for (int jj = 0; jj < ND; ++jj) a += wr[jj] * hv[jj];
        sdec[i] = sW2v[k] * tanh_(a);
    }
    __syncthreads();

    if (tid < NT) {
        float a = 0.0f;
        for (int k = 0; k < NH; ++k) a += sdec[tid * NH + k];
        sat[tid] = a; // b2 cancels in softmax
    }
    __syncthreads();
    if (tid == 0) {
        float m = -1e30f;
        for (int t = 0; t < NT; ++t) m = fmaxf(m, sat[t]);
        float e[NT], s = 0.0f;
        for (int t = 0; t < NT; ++t) { e[t] = __expf(sat[t] - m); s += e[t]; }
        const float inv = rcp_(s);
        for (int t = 0; t < NT; ++t) sat[t] = e[t] * inv;
    }
    __syncthreads();

    if (tid < NH) {
        float a = 0.0f;
        for (int t = 0; t < NT; ++t) a += sat[t] * shs[t * NH + tid];
        sctx[tid] = a;
    }
    __syncthreads();

    // ---- decoder LSTM (h=c=0): gate g from registers held since t=0 ----
    if (wave > 0 && g < NG) {
        float a = bd;
#pragma unroll
        for (int d = 0; d < 45; ++d) a += wd[d] * sctx[d];
        sg[g] = a;
    }
    __syncthreads();
    if (tid < NH) {
        const float ig = sigf(sg[tid]);
        const float gg = tanh_(sg[2 * NH + tid]);
        const float og = sigf(sg[3 * NH + tid]);
        sh1v[tid] = og * tanh_(ig * gg); // c0 = 0
    }
    __syncthreads();

    // ---- final fc: y = [h1, ctx] @ Wfc.T + bfc ----
    if (tid < 45) {
        const float* wr = sWfc + tid * (2 * NH);
        float a = sbfcv[tid];
        for (int jj = 0; jj < NH; ++jj) a += wr[jj] * sh1v[jj];
        for (int jj = 0; jj < NH; ++jj) a += wr[NH + jj] * sctx[jj];
        out[tid] = a;
    }
}

extern "C" void kernel_launch(void* const* d_in, const int* in_sizes, int n_in,
                              void* d_out, int out_size, void* d_ws, size_t ws_size,
                              hipStream_t stream) {
    const float* X     = (const float*)d_in[0];
    const float* Wa    = (const float*)d_in[1];
    // d_in[2] = ba — dead
    const float* Wih_e = (const float*)d_in[3];
    const float* Whh_e = (const float*)d_in[4];
    const float* bih_e = (const float*)d_in[5];
    const float* bhh_e = (const float*)d_in[6];
    const float* W1    = (const float*)d_in[7];
    const float* b1    = (const float*)d_in[8];
    const float* W2    = (const float*)d_in[9];
    // d_in[10] = b2 — dead
    const float* Wih_d = (const float*)d_in[11];
    // d_in[12] = Whh_d — dead
    const float* bih_d = (const float*)d_in[13];
    const float* bhh_d = (const float*)d_in[14];
    const float* Wfc   = (const float*)d_in[15];
    const float* bfc   = (const float*)d_in[16];
    float* out = (float*)d_out;

    darnn_kernel<<<dim3(1), dim3(256), 0, stream>>>(
        X, Wa, Wih_e, Whh_e, bih_e, bhh_e, W1, b1, W2,
        Wih_d, bih_d, bhh_d, Wfc, bfc, out);
}